// Round 2
// baseline (1316.859 us; speedup 1.0000x reference)
//
#include <hip/hip_runtime.h>
#include <hip/hip_bf16.h>

typedef __hip_bfloat16 bf16;
typedef __attribute__((ext_vector_type(8))) short short8;
typedef __attribute__((ext_vector_type(4))) short short4v;
typedef __attribute__((ext_vector_type(4))) float floatx4;

#define N_BATCH 16
#define NBQ 56
#define SEQ (NBQ*NBQ)          // 3136
#define DIM 384
#define DI 768
#define MROWS (N_BATCH*SEQ)    // 50176
#define NSEG 49
#define SEGLEN 64

__device__ __forceinline__ float b2f(bf16 v){ return __bfloat162float(v); }
__device__ __forceinline__ bf16 f2b(float v){ return __float2bfloat16(v); }

// dual-dtype input load / output store (flag: 1 = fp32 tensors, 0 = bf16)
__device__ __forceinline__ float ldin(const void* p, size_t i, int f32){
    return f32 ? ((const float*)p)[i] : __bfloat162float(((const bf16*)p)[i]);
}
__device__ __forceinline__ void stout(void* p, size_t i, int f32, float v){
    if (f32) ((float*)p)[i] = v; else ((bf16*)p)[i] = __float2bfloat16(v);
}

__device__ __forceinline__ void gl2lds16(const void* g, void* l) {
    __builtin_amdgcn_global_load_lds((const __attribute__((address_space(1))) void*)g,
                                     (__attribute__((address_space(3))) void*)l, 16, 0, 0);
}

// ---------------- dtype detection: bf16-NaN patterns only occur if data is fp32 ----------------
__global__ void detect_kernel(const unsigned short* __restrict__ x, int* __restrict__ flag) {
    __shared__ int cnt;
    if (threadIdx.x == 0) cnt = 0;
    __syncthreads();
    int c = 0;
    for (int i = threadIdx.x; i < 16384; i += 256) {
        unsigned short u = x[i];
        if ((u & 0x7F80) == 0x7F80) ++c;   // bf16 exp==0xFF (inf/NaN)
    }
    if (c) atomicAdd(&cnt, c);
    __syncthreads();
    if (threadIdx.x == 0) *flag = cnt ? 1 : 0;
}

// ---------------- LayerNorm: one wave per row of 384; dual-dtype in, bf16 out ----------------
__global__ __launch_bounds__(64) void ln_kernel(const void* __restrict__ x,
        const void* __restrict__ w, const void* __restrict__ b,
        bf16* __restrict__ y, size_t row_off, const int* __restrict__ flag) {
    const int f32 = *flag;
    const size_t row = row_off + blockIdx.x;
    const int lane = threadIdx.x;
    float v[6]; float s = 0.f;
    #pragma unroll
    for (int j = 0; j < 6; ++j) { v[j] = ldin(x, row*DIM + lane + j*64, f32); s += v[j]; }
    #pragma unroll
    for (int o = 32; o; o >>= 1) s += __shfl_xor(s, o);
    const float mu = s * (1.f/DIM);
    float s2 = 0.f;
    #pragma unroll
    for (int j = 0; j < 6; ++j) { float d = v[j]-mu; s2 += d*d; }
    #pragma unroll
    for (int o = 32; o; o >>= 1) s2 += __shfl_xor(s2, o);
    const float inv = rsqrtf(s2*(1.f/DIM) + 1e-5f);
    bf16* yr = y + (size_t)blockIdx.x * DIM;   // chunk-local output row
    #pragma unroll
    for (int j = 0; j < 6; ++j) {
        int c = lane + j*64;
        yr[c] = f2b((v[j]-mu)*inv*ldin(w, c, f32) + ldin(b, c, f32));
    }
}

// ---------------- depthwise 3x3 conv: vectorized rolling-window version ----------------
__device__ __forceinline__ floatx4 ld_tok4(const bf16* p){
    short4v s = *(const short4v*)p;
    floatx4 f;
    #pragma unroll
    for (int k = 0; k < 4; ++k) {
        unsigned int u = ((unsigned int)(unsigned short)s[k]) << 16;
        f[k] = __uint_as_float(u);
    }
    return f;
}

__global__ __launch_bounds__(192) void dwconv_kernel(const bf16* __restrict__ h,
        const void* __restrict__ w, const void* __restrict__ bias,
        bf16* __restrict__ out, const int* __restrict__ flag) {
    const int f32 = *flag;
    const int tid = threadIdx.x;
    const int c4  = tid % 96;                 // channel quad 0..95
    const int j   = blockIdx.x*2 + tid/96;    // image column 0..55
    const int i0  = blockIdx.y*8;             // 7 strips of 8 rows
    const int n   = blockIdx.z;               // chunk-local batch
    const int c0  = c4*4;
    const bf16* hn = h + (size_t)n*SEQ*DIM + c0;

    floatx4 wgt[9];
    #pragma unroll
    for (int t = 0; t < 9; ++t)
        #pragma unroll
        for (int k = 0; k < 4; ++k)
            wgt[t][k] = ldin(w, (size_t)(c0+k)*9 + t, f32);
    floatx4 bv;
    #pragma unroll
    for (int k = 0; k < 4; ++k) bv[k] = ldin(bias, c0+k, f32);

    const floatx4 zero = (floatx4){0.f,0.f,0.f,0.f};
    floatx4 win[3][3];                         // [row: top/mid/bot][col: j-1,j,j+1]
    #pragma unroll
    for (int dj = 0; dj < 3; ++dj) {
        const int jj = j + dj - 1;
        const bool jok = (unsigned)jj < NBQ;
        win[0][dj] = (jok && i0 > 0) ? ld_tok4(hn + ((size_t)((i0-1)*NBQ + jj))*DIM) : zero;
        win[1][dj] =  jok            ? ld_tok4(hn + ((size_t)( i0   *NBQ + jj))*DIM) : zero;
    }
    bf16* on = out + (size_t)n*SEQ*DIM + c0;
    #pragma unroll
    for (int r = 0; r < 8; ++r) {
        const int i = i0 + r;
        #pragma unroll
        for (int dj = 0; dj < 3; ++dj) {
            const int jj = j + dj - 1;
            const bool ok = ((unsigned)jj < NBQ) && (i+1 < NBQ);
            win[2][dj] = ok ? ld_tok4(hn + ((size_t)((i+1)*NBQ + jj))*DIM) : zero;
        }
        floatx4 acc = bv;
        #pragma unroll
        for (int di = 0; di < 3; ++di)
            #pragma unroll
            for (int dj = 0; dj < 3; ++dj)
                #pragma unroll
                for (int k = 0; k < 4; ++k)
                    acc[k] += win[di][dj][k] * wgt[di*3+dj][k];
        short4v o;
        #pragma unroll
        for (int k = 0; k < 4; ++k) { bf16 t = f2b(acc[k]); o[k] = *(short*)&t; }
        *(short4v*)(on + ((size_t)(i*NBQ + j))*DIM) = o;
        #pragma unroll
        for (int dj = 0; dj < 3; ++dj) { win[0][dj] = win[1][dj]; win[1][dj] = win[2][dj]; }
    }
}

// ---------------- segmented minGRU scan ----------------
__global__ __launch_bounds__(64) void scan_p1(const bf16* __restrict__ G,
        float* __restrict__ Aseg, float* __restrict__ Bseg, int dir) {
    const int c = blockIdx.x*64 + threadIdx.x;   // 0..767
    const int s = blockIdx.y;                    // 0..48
    const int n = blockIdx.z;
    const bf16* base = G + (size_t)n*SEQ*(2*DI) + c;
    float A = 1.f, B = 0.f;
    #pragma unroll 4
    for (int u = 0; u < SEGLEN; ++u) {
        const int t = dir ? (SEQ-1 - (s*SEGLEN + u)) : (s*SEGLEN + u);
        const bf16* p = base + (size_t)t*(2*DI);
        float hid = b2f(p[0]), gate = b2f(p[DI]);
        float z  = 1.f/(1.f + __expf(-gate));
        float tl = hid >= 0.f ? hid + 0.5f : 1.f/(1.f + __expf(-hid));
        float a = 1.f - z;
        A *= a;
        B = a*B + z*tl;
    }
    const size_t idx = ((size_t)n*NSEG + s)*DI + c;
    Aseg[idx] = A; Bseg[idx] = B;
}

__global__ __launch_bounds__(64) void scan_p2(const float* __restrict__ Aseg,
        const float* __restrict__ Bseg, float* __restrict__ Pseg) {
    const int c = blockIdx.x*64 + threadIdx.x;
    const int n = blockIdx.y;
    float P = 0.f;
    for (int s = 0; s < NSEG; ++s) {
        const size_t idx = ((size_t)n*NSEG + s)*DI + c;
        Pseg[idx] = P;
        P = Aseg[idx]*P + Bseg[idx];
    }
}

__global__ __launch_bounds__(64) void scan_p3(bf16* __restrict__ G,
        const float* __restrict__ Pseg, int dir) {
    const int c = blockIdx.x*64 + threadIdx.x;
    const int s = blockIdx.y;
    const int n = blockIdx.z;
    bf16* base = G + (size_t)n*SEQ*(2*DI) + c;
    float h = Pseg[((size_t)n*NSEG + s)*DI + c];
    #pragma unroll 4
    for (int u = 0; u < SEGLEN; ++u) {
        const int t = dir ? (SEQ-1 - (s*SEGLEN + u)) : (s*SEGLEN + u);
        bf16* p = base + (size_t)t*(2*DI);
        float hid = b2f(p[0]), gate = b2f(p[DI]);
        float z  = 1.f/(1.f + __expf(-gate));
        float tl = hid >= 0.f ? hid + 0.5f : 1.f/(1.f + __expf(-hid));
        h = (1.f - z)*h + z*tl;
        p[0] = f2b(h);
    }
}

// ---------------- small weight transpose: dual-dtype in, bf16 out ----------------
__global__ void transpose_kernel(const void* __restrict__ src, bf16* __restrict__ dst,
                                 int R, int C, const int* __restrict__ flag) {
    const int f32 = *flag;
    int idx = blockIdx.x*256 + threadIdx.x;
    if (idx >= R*C) return;
    int r = idx / C, c = idx - r*C;
    dst[(size_t)c*R + r] = f2b(ldin(src, idx, f32));
}

// ---------------- 128x128 bf16 MFMA GEMM: XOR-swizzled LDS, double-buffered,
// XCD-aware block swizzle ----------------
// LDS tile: 128 rows x 64 shorts. Logical 16B-block l of row r stored at
// physical block (l ^ (r&7)).
// Pipeline (T3-min): stage(next) issued BEFORE compute(cur); the vmcnt(0)
// inside the trailing __syncthreads() drains loads that had the full MFMA
// phase to land. XCD swizzle puts the N-tiles sharing one A-panel on the
// same XCD -> A staged from L2, not HBM.
// MODE 0: store bf16; 1: +resid dual; 2: +bias gelu bf16; 3: +bias +resid dual
template<int MODE>
__global__ __launch_bounds__(256, 2) void gemm_kernel(
        const bf16* __restrict__ A, int lda,
        const bf16* __restrict__ Bt,
        void* __restrict__ C, int ldc, int K, size_t row_off,
        const void* __restrict__ bias, const void* __restrict__ resid,
        const int* __restrict__ flag) {
    __shared__ __align__(16) short lsA[2][128*64];
    __shared__ __align__(16) short lsB[2][128*64];
    const int tid  = threadIdx.x;

    // bijective XCD swizzle (8 XCDs); consecutive swizzled ids walk gridDim.x
    // fastest, so same-A-panel blocks are contiguous within one XCD chunk.
    const int nwg = gridDim.x * gridDim.y;
    int bid = blockIdx.y * gridDim.x + blockIdx.x;
    {
        const int q = nwg >> 3, r = nwg & 7;
        const int xcd = bid & 7, ix = bid >> 3;
        bid = (xcd < r ? xcd*(q+1) : r*(q+1) + (xcd-r)*q) + ix;
    }
    const int tn0  = (bid % gridDim.x) * 128;
    const int tm0  = (bid / gridDim.x) * 128;

    const int lane = tid & 63;
    const int wave = tid >> 6;
    const int wm = (wave & 1) * 64;
    const int wn = (wave >> 1) * 64;
    const int row16 = lane & 15;
    const int quad  = lane >> 4;
    const int r7    = row16 & 7;           // row&7 for all fragment rows

    floatx4 acc[4][4];
    #pragma unroll
    for (int i = 0; i < 4; ++i)
        #pragma unroll
        for (int j = 0; j < 4; ++j)
            acc[i][j] = (floatx4){0.f, 0.f, 0.f, 0.f};

    // staging swizzle constants (per-thread, loop-invariant)
    const int so_row = tid >> 3;                 // row within a 32-row slab
    const int so_pb  = tid & 7;                  // physical 16B block
    const int so_lb  = so_pb ^ (so_row & 7);     // logical 16B block

    const char* Abase = (const char*)A + (size_t)tm0*((size_t)lda*2);
    const char* Bbase = (const char*)Bt + (size_t)tn0*((size_t)K*2);
    const int nt = K >> 6;

    auto stage = [&](int buf, int t) {
        const char* Ab = Abase + (size_t)t*128;     // k0 = t*64 -> *2 bytes
        const char* Bb = Bbase + (size_t)t*128;
        #pragma unroll
        for (int it = 0; it < 4; ++it) {
            int row = it*32 + so_row;
            gl2lds16(Ab + (size_t)row*((size_t)lda*2) + so_lb*16,
                     (char*)(lsA[buf]) + row*128 + so_pb*16);
        }
        #pragma unroll
        for (int it = 0; it < 4; ++it) {
            int row = it*32 + so_row;
            gl2lds16(Bb + (size_t)row*((size_t)K*2) + so_lb*16,
                     (char*)(lsB[buf]) + row*128 + so_pb*16);
        }
    };

    stage(0, 0);
    __syncthreads();
    int cur = 0;
    for (int t = 0; t < nt; ++t) {
        if (t + 1 < nt) stage(cur ^ 1, t + 1);   // prefetch next K-tile
        const short* la = lsA[cur];
        const short* lb_ = lsB[cur];
        #pragma unroll
        for (int kk = 0; kk < 64; kk += 32) {
            const int lb = (kk >> 3) + quad;          // logical block
            const int pb = (lb ^ r7) * 8;             // physical short offset
            short8 af[4], bfr[4];
            #pragma unroll
            for (int i = 0; i < 4; ++i)
                af[i] = *(const short8*)(la + (wm + i*16 + row16)*64 + pb);
            #pragma unroll
            for (int j = 0; j < 4; ++j)
                bfr[j] = *(const short8*)(lb_ + (wn + j*16 + row16)*64 + pb);
            #pragma unroll
            for (int i = 0; i < 4; ++i)
                #pragma unroll
                for (int j = 0; j < 4; ++j)
                    acc[i][j] = __builtin_amdgcn_mfma_f32_16x16x32_bf16(af[i], bfr[j], acc[i][j], 0, 0, 0);
        }
        if (t + 1 < nt) { __syncthreads(); cur ^= 1; }
    }

    const int f32 = (MODE == 0) ? 0 : *flag;
    #pragma unroll
    for (int i = 0; i < 4; ++i) {
        #pragma unroll
        for (int j = 0; j < 4; ++j) {
            #pragma unroll
            for (int r = 0; r < 4; ++r) {
                const int gm = tm0 + wm + i*16 + quad*4 + r;
                const int gn = tn0 + wn + j*16 + row16;
                float v = acc[i][j][r];
                if (MODE == 0) {
                    ((bf16*)C)[(size_t)gm*ldc + gn] = f2b(v);
                } else if (MODE == 1) {
                    size_t gi = (row_off + gm)*(size_t)ldc + gn;
                    v += ldin(resid, gi, f32);
                    stout(C, gi, f32, v);
                } else if (MODE == 2) {
                    v += ldin(bias, gn, f32);
                    v = 0.5f*v*(1.f + erff(v*0.70710678118f));
                    ((bf16*)C)[(size_t)gm*ldc + gn] = f2b(v);
                } else {
                    size_t gi = (row_off + gm)*(size_t)ldc + gn;
                    v += ldin(bias, gn, f32) + ldin(resid, gi, f32);
                    stout(C, gi, f32, v);
                }
            }
        }
    }
}

extern "C" void kernel_launch(void* const* d_in, const int* in_sizes, int n_in,
                              void* d_out, int out_size, void* d_ws, size_t ws_size,
                              hipStream_t stream) {
    const void* x       = d_in[0];
    const void* norm_w  = d_in[1];
    const void* norm_b  = d_in[2];
    const void* dw_w    = d_in[3];
    const void* dw_b    = d_in[4];
    const void* whg1    = d_in[5];
    const void* wout1   = d_in[6];
    const void* whg2    = d_in[7];
    const void* wout2   = d_in[8];
    const void* norm2_w = d_in[9];
    const void* norm2_b = d_in[10];
    const void* p1_w    = d_in[11];
    const void* p1_b    = d_in[12];
    const void* p2_w    = d_in[13];
    const void* p2_b    = d_in[14];
    void* out = d_out;
    char* ws = (char*)d_ws;

    const size_t WSZ = 5898240;   // transposed weights (bf16)

    int CH = 16;
    for (;;) {
        size_t need = 256 + WSZ + (size_t)CH * SEQ * 4608;
        if (need <= ws_size || CH == 2) break;
        CH >>= 1;
    }
    const int NC = N_BATCH / CH;
    const int CHROWS = CH * SEQ;

    int* flag = (int*)ws;
    char* wb = ws + 256;
    bf16* WhgT1  = (bf16*)(wb);                  // 1536 x 384
    bf16* WhgT2  = (bf16*)(wb + 1179648);        // 1536 x 384
    bf16* WoutT1 = (bf16*)(wb + 2359296);        // 384 x 768
    bf16* WoutT2 = (bf16*)(wb + 2949120);        // 384 x 768
    bf16* P1T    = (bf16*)(wb + 3538944);        // 1536 x 384
    bf16* P2T    = (bf16*)(wb + 4718592);        // 384 x 1536
    char* dyn = ws + 256 + WSZ;
    bf16* h_ln_c   = (bf16*)(dyn);
    bf16* h_conv_c = (bf16*)(dyn + (size_t)CHROWS*DIM*2);
    bf16* Gbuf     = (bf16*)(dyn + 2*(size_t)CHROWS*DIM*2);
    bf16* mid_ln_c = h_ln_c;
    float* Aseg = (float*)h_ln_c;
    float* Bseg = Aseg + (size_t)CH*NSEG*DI;
    float* Pseg = Bseg + (size_t)CH*NSEG*DI;

    detect_kernel<<<1, 256, 0, stream>>>((const unsigned short*)x, flag);

    transpose_kernel<<<(384*1536+255)/256, 256, 0, stream>>>(whg1, WhgT1, 384, 1536, flag);
    transpose_kernel<<<(384*1536+255)/256, 256, 0, stream>>>(whg2, WhgT2, 384, 1536, flag);
    transpose_kernel<<<(768*384+255)/256, 256, 0, stream>>>(wout1, WoutT1, 768, 384, flag);
    transpose_kernel<<<(768*384+255)/256, 256, 0, stream>>>(wout2, WoutT2, 768, 384, flag);
    transpose_kernel<<<(384*1536+255)/256, 256, 0, stream>>>(p1_w, P1T, 384, 1536, flag);
    transpose_kernel<<<(1536*384+255)/256, 256, 0, stream>>>(p2_w, P2T, 1536, 384, flag);

    for (int pass = 0; pass < 2; ++pass) {
        const bf16* WhgT  = pass ? WhgT2  : WhgT1;
        const bf16* WoutT = pass ? WoutT2 : WoutT1;
        for (int ck = 0; ck < NC; ++ck) {
            const size_t roff = (size_t)ck * CHROWS;
            if (pass == 0 || NC > 1) {
                ln_kernel<<<CHROWS, 64, 0, stream>>>(x, norm_w, norm_b, h_ln_c, roff, flag);
                dwconv_kernel<<<dim3(28, 7, CH), 192, 0, stream>>>(h_ln_c, dw_w, dw_b, h_conv_c, flag);
            }
            gemm_kernel<0><<<dim3(1536/128, CHROWS/128), 256, 0, stream>>>(
                h_conv_c, DIM, WhgT, Gbuf, 2*DI, DIM, 0, nullptr, nullptr, flag);
            scan_p1<<<dim3(12, NSEG, CH), 64, 0, stream>>>(Gbuf, Aseg, Bseg, pass);
            scan_p2<<<dim3(12, CH), 64, 0, stream>>>(Aseg, Bseg, Pseg);
            scan_p3<<<dim3(12, NSEG, CH), 64, 0, stream>>>(Gbuf, Pseg, pass);
            const void* resid = pass ? (const void*)out : x;
            gemm_kernel<1><<<dim3(DIM/128, CHROWS/128), 256, 0, stream>>>(
                Gbuf, 2*DI, WoutT, out, DIM, DI, roff, nullptr, resid, flag);
        }
    }

    for (int ck = 0; ck < NC; ++ck) {
        const size_t roff = (size_t)ck * CHROWS;
        ln_kernel<<<CHROWS, 64, 0, stream>>>(out, norm2_w, norm2_b, mid_ln_c, roff, flag);
        gemm_kernel<2><<<dim3(1536/128, CHROWS/128), 256, 0, stream>>>(
            mid_ln_c, DIM, P1T, Gbuf, 1536, DIM, 0, p1_b, nullptr, flag);
        gemm_kernel<3><<<dim3(DIM/128, CHROWS/128), 256, 0, stream>>>(
            Gbuf, 1536, P2T, out, DIM, 1536, roff, p2_b, out, flag);
    }
}

// Round 3
// 1129.345 us; speedup vs baseline: 1.1660x; 1.1660x over previous
//
#include <hip/hip_runtime.h>
#include <hip/hip_bf16.h>

typedef __hip_bfloat16 bf16;
typedef __attribute__((ext_vector_type(8))) short short8;
typedef __attribute__((ext_vector_type(4))) short short4v;
typedef __attribute__((ext_vector_type(4))) float floatx4;

#define N_BATCH 16
#define NBQ 56
#define SEQ (NBQ*NBQ)          // 3136
#define DIM 384
#define DI 768
#define MROWS (N_BATCH*SEQ)    // 50176
#define NSEG 49
#define SEGLEN 64

__device__ __forceinline__ float b2f(bf16 v){ return __bfloat162float(v); }
__device__ __forceinline__ bf16 f2b(float v){ return __float2bfloat16(v); }

// dual-dtype input load / output store (flag: 1 = fp32 tensors, 0 = bf16)
__device__ __forceinline__ float ldin(const void* p, size_t i, int f32){
    return f32 ? ((const float*)p)[i] : __bfloat162float(((const bf16*)p)[i]);
}
__device__ __forceinline__ void stout(void* p, size_t i, int f32, float v){
    if (f32) ((float*)p)[i] = v; else ((bf16*)p)[i] = __float2bfloat16(v);
}

__device__ __forceinline__ void gl2lds16(const void* g, void* l) {
    __builtin_amdgcn_global_load_lds((const __attribute__((address_space(1))) void*)g,
                                     (__attribute__((address_space(3))) void*)l, 16, 0, 0);
}

// ---------------- dtype detection: bf16-NaN patterns only occur if data is fp32 ----------------
__global__ void detect_kernel(const unsigned short* __restrict__ x, int* __restrict__ flag) {
    __shared__ int cnt;
    if (threadIdx.x == 0) cnt = 0;
    __syncthreads();
    int c = 0;
    for (int i = threadIdx.x; i < 16384; i += 256) {
        unsigned short u = x[i];
        if ((u & 0x7F80) == 0x7F80) ++c;   // bf16 exp==0xFF (inf/NaN)
    }
    if (c) atomicAdd(&cnt, c);
    __syncthreads();
    if (threadIdx.x == 0) *flag = cnt ? 1 : 0;
}

// ---------------- LayerNorm: one wave per row of 384; dual-dtype in, bf16 out ----------------
__global__ __launch_bounds__(64) void ln_kernel(const void* __restrict__ x,
        const void* __restrict__ w, const void* __restrict__ b,
        bf16* __restrict__ y, size_t row_off, const int* __restrict__ flag) {
    const int f32 = *flag;
    const size_t row = row_off + blockIdx.x;
    const int lane = threadIdx.x;
    float v[6]; float s = 0.f;
    #pragma unroll
    for (int j = 0; j < 6; ++j) { v[j] = ldin(x, row*DIM + lane + j*64, f32); s += v[j]; }
    #pragma unroll
    for (int o = 32; o; o >>= 1) s += __shfl_xor(s, o);
    const float mu = s * (1.f/DIM);
    float s2 = 0.f;
    #pragma unroll
    for (int j = 0; j < 6; ++j) { float d = v[j]-mu; s2 += d*d; }
    #pragma unroll
    for (int o = 32; o; o >>= 1) s2 += __shfl_xor(s2, o);
    const float inv = rsqrtf(s2*(1.f/DIM) + 1e-5f);
    bf16* yr = y + (size_t)blockIdx.x * DIM;   // chunk-local output row
    #pragma unroll
    for (int j = 0; j < 6; ++j) {
        int c = lane + j*64;
        yr[c] = f2b((v[j]-mu)*inv*ldin(w, c, f32) + ldin(b, c, f32));
    }
}

// ---------------- depthwise 3x3 conv: vectorized rolling-window version ----------------
__device__ __forceinline__ floatx4 ld_tok4(const bf16* p){
    short4v s = *(const short4v*)p;
    floatx4 f;
    #pragma unroll
    for (int k = 0; k < 4; ++k) {
        unsigned int u = ((unsigned int)(unsigned short)s[k]) << 16;
        f[k] = __uint_as_float(u);
    }
    return f;
}

__global__ __launch_bounds__(192) void dwconv_kernel(const bf16* __restrict__ h,
        const void* __restrict__ w, const void* __restrict__ bias,
        bf16* __restrict__ out, const int* __restrict__ flag) {
    const int f32 = *flag;
    const int tid = threadIdx.x;
    const int c4  = tid % 96;                 // channel quad 0..95
    const int j   = blockIdx.x*2 + tid/96;    // image column 0..55
    const int i0  = blockIdx.y*8;             // 7 strips of 8 rows
    const int n   = blockIdx.z;               // chunk-local batch
    const int c0  = c4*4;
    const bf16* hn = h + (size_t)n*SEQ*DIM + c0;

    floatx4 wgt[9];
    #pragma unroll
    for (int t = 0; t < 9; ++t)
        #pragma unroll
        for (int k = 0; k < 4; ++k)
            wgt[t][k] = ldin(w, (size_t)(c0+k)*9 + t, f32);
    floatx4 bv;
    #pragma unroll
    for (int k = 0; k < 4; ++k) bv[k] = ldin(bias, c0+k, f32);

    const floatx4 zero = (floatx4){0.f,0.f,0.f,0.f};
    floatx4 win[3][3];                         // [row: top/mid/bot][col: j-1,j,j+1]
    #pragma unroll
    for (int dj = 0; dj < 3; ++dj) {
        const int jj = j + dj - 1;
        const bool jok = (unsigned)jj < NBQ;
        win[0][dj] = (jok && i0 > 0) ? ld_tok4(hn + ((size_t)((i0-1)*NBQ + jj))*DIM) : zero;
        win[1][dj] =  jok            ? ld_tok4(hn + ((size_t)( i0   *NBQ + jj))*DIM) : zero;
    }
    bf16* on = out + (size_t)n*SEQ*DIM + c0;
    #pragma unroll
    for (int r = 0; r < 8; ++r) {
        const int i = i0 + r;
        #pragma unroll
        for (int dj = 0; dj < 3; ++dj) {
            const int jj = j + dj - 1;
            const bool ok = ((unsigned)jj < NBQ) && (i+1 < NBQ);
            win[2][dj] = ok ? ld_tok4(hn + ((size_t)((i+1)*NBQ + jj))*DIM) : zero;
        }
        floatx4 acc = bv;
        #pragma unroll
        for (int di = 0; di < 3; ++di)
            #pragma unroll
            for (int dj = 0; dj < 3; ++dj)
                #pragma unroll
                for (int k = 0; k < 4; ++k)
                    acc[k] += win[di][dj][k] * wgt[di*3+dj][k];
        short4v o;
        #pragma unroll
        for (int k = 0; k < 4; ++k) { bf16 t = f2b(acc[k]); o[k] = *(short*)&t; }
        *(short4v*)(on + ((size_t)(i*NBQ + j))*DIM) = o;
        #pragma unroll
        for (int dj = 0; dj < 3; ++dj) { win[0][dj] = win[1][dj]; win[1][dj] = win[2][dj]; }
    }
}

// ---------------- segmented minGRU scan ----------------
__global__ __launch_bounds__(64) void scan_p1(const bf16* __restrict__ G,
        float* __restrict__ Aseg, float* __restrict__ Bseg, int dir) {
    const int c = blockIdx.x*64 + threadIdx.x;   // 0..767
    const int s = blockIdx.y;                    // 0..48
    const int n = blockIdx.z;
    const bf16* base = G + (size_t)n*SEQ*(2*DI) + c;
    float A = 1.f, B = 0.f;
    #pragma unroll 4
    for (int u = 0; u < SEGLEN; ++u) {
        const int t = dir ? (SEQ-1 - (s*SEGLEN + u)) : (s*SEGLEN + u);
        const bf16* p = base + (size_t)t*(2*DI);
        float hid = b2f(p[0]), gate = b2f(p[DI]);
        float z  = 1.f/(1.f + __expf(-gate));
        float tl = hid >= 0.f ? hid + 0.5f : 1.f/(1.f + __expf(-hid));
        float a = 1.f - z;
        A *= a;
        B = a*B + z*tl;
    }
    const size_t idx = ((size_t)n*NSEG + s)*DI + c;
    Aseg[idx] = A; Bseg[idx] = B;
}

__global__ __launch_bounds__(64) void scan_p2(const float* __restrict__ Aseg,
        const float* __restrict__ Bseg, float* __restrict__ Pseg) {
    const int c = blockIdx.x*64 + threadIdx.x;
    const int n = blockIdx.y;
    float P = 0.f;
    for (int s = 0; s < NSEG; ++s) {
        const size_t idx = ((size_t)n*NSEG + s)*DI + c;
        Pseg[idx] = P;
        P = Aseg[idx]*P + Bseg[idx];
    }
}

__global__ __launch_bounds__(64) void scan_p3(bf16* __restrict__ G,
        const float* __restrict__ Pseg, int dir) {
    const int c = blockIdx.x*64 + threadIdx.x;
    const int s = blockIdx.y;
    const int n = blockIdx.z;
    bf16* base = G + (size_t)n*SEQ*(2*DI) + c;
    float h = Pseg[((size_t)n*NSEG + s)*DI + c];
    #pragma unroll 4
    for (int u = 0; u < SEGLEN; ++u) {
        const int t = dir ? (SEQ-1 - (s*SEGLEN + u)) : (s*SEGLEN + u);
        bf16* p = base + (size_t)t*(2*DI);
        float hid = b2f(p[0]), gate = b2f(p[DI]);
        float z  = 1.f/(1.f + __expf(-gate));
        float tl = hid >= 0.f ? hid + 0.5f : 1.f/(1.f + __expf(-hid));
        h = (1.f - z)*h + z*tl;
        p[0] = f2b(h);
    }
}

// ---------------- small weight transpose: dual-dtype in, bf16 out ----------------
__global__ void transpose_kernel(const void* __restrict__ src, bf16* __restrict__ dst,
                                 int R, int C, const int* __restrict__ flag) {
    const int f32 = *flag;
    int idx = blockIdx.x*256 + threadIdx.x;
    if (idx >= R*C) return;
    int r = idx / C, c = idx - r*C;
    dst[(size_t)c*R + r] = f2b(ldin(src, idx, f32));
}

// ---------------- 128x128 bf16 MFMA GEMM: XOR-swizzled LDS + XCD-aware block swizzle ----------------
// Single 32KB LDS buffer, 2-barrier K-loop (proven round-1 structure; dbuf was
// the m132 trap: 64KB LDS -> occupancy drop -> -35%). XCD swizzle keeps the
// N-tiles sharing one A-panel on one XCD -> stage drain fed from L2/L3
// (FETCH 278MB -> 25MB measured in round 2).
// LDS tile: 128 rows x 64 shorts. Logical 16B-block l of row r stored at
// physical block (l ^ (r&7)) -> uniform bank usage on ds_read_b128.
// MODE 0: store bf16; 1: +resid dual; 2: +bias gelu bf16; 3: +bias +resid dual
template<int MODE>
__global__ __launch_bounds__(256, 2) void gemm_kernel(
        const bf16* __restrict__ A, int lda,
        const bf16* __restrict__ Bt,
        void* __restrict__ C, int ldc, int K, size_t row_off,
        const void* __restrict__ bias, const void* __restrict__ resid,
        const int* __restrict__ flag) {
    __shared__ __align__(16) short lsA[128*64];
    __shared__ __align__(16) short lsB[128*64];
    const int tid  = threadIdx.x;

    // bijective XCD swizzle (8 XCDs): consecutive swizzled ids walk gridDim.x
    // fastest, so same-A-panel blocks are contiguous within one XCD chunk.
    const int nwg = gridDim.x * gridDim.y;
    int bid = blockIdx.y * gridDim.x + blockIdx.x;
    {
        const int q = nwg >> 3, r = nwg & 7;
        const int xcd = bid & 7, ix = bid >> 3;
        bid = (xcd < r ? xcd*(q+1) : r*(q+1) + (xcd-r)*q) + ix;
    }
    const int tn0  = (bid % gridDim.x) * 128;
    const int tm0  = (bid / gridDim.x) * 128;

    const int lane = tid & 63;
    const int wave = tid >> 6;
    const int wm = (wave & 1) * 64;
    const int wn = (wave >> 1) * 64;
    const int row16 = lane & 15;
    const int quad  = lane >> 4;
    const int r7    = row16 & 7;           // row&7 for all fragment rows

    floatx4 acc[4][4];
    #pragma unroll
    for (int i = 0; i < 4; ++i)
        #pragma unroll
        for (int j = 0; j < 4; ++j)
            acc[i][j] = (floatx4){0.f, 0.f, 0.f, 0.f};

    // staging swizzle constants (per-thread, loop-invariant)
    const int so_row = tid >> 3;                 // row within a 32-row slab
    const int so_pb  = tid & 7;                  // physical 16B block
    const int so_lb  = so_pb ^ (so_row & 7);     // logical 16B block

    for (int k0 = 0; k0 < K; k0 += 64) {
        const char* Ab = (const char*)(A + (size_t)tm0*lda + k0);
        const char* Bb = (const char*)(Bt + (size_t)tn0*K + k0);
        #pragma unroll
        for (int it = 0; it < 4; ++it) {
            int row = it*32 + so_row;
            gl2lds16(Ab + (size_t)row*((size_t)lda*2) + so_lb*16,
                     (char*)lsA + row*128 + so_pb*16);
        }
        #pragma unroll
        for (int it = 0; it < 4; ++it) {
            int row = it*32 + so_row;
            gl2lds16(Bb + (size_t)row*((size_t)K*2) + so_lb*16,
                     (char*)lsB + row*128 + so_pb*16);
        }
        __syncthreads();
        #pragma unroll
        for (int kk = 0; kk < 64; kk += 32) {
            const int lb = (kk >> 3) + quad;          // logical block
            const int pb = (lb ^ r7) * 8;             // physical short offset
            short8 af[4], bfr[4];
            #pragma unroll
            for (int i = 0; i < 4; ++i)
                af[i] = *(const short8*)(lsA + (wm + i*16 + row16)*64 + pb);
            #pragma unroll
            for (int j = 0; j < 4; ++j)
                bfr[j] = *(const short8*)(lsB + (wn + j*16 + row16)*64 + pb);
            #pragma unroll
            for (int i = 0; i < 4; ++i)
                #pragma unroll
                for (int j = 0; j < 4; ++j)
                    acc[i][j] = __builtin_amdgcn_mfma_f32_16x16x32_bf16(af[i], bfr[j], acc[i][j], 0, 0, 0);
        }
        __syncthreads();
    }

    const int f32 = (MODE == 0) ? 0 : *flag;
    #pragma unroll
    for (int i = 0; i < 4; ++i) {
        #pragma unroll
        for (int j = 0; j < 4; ++j) {
            #pragma unroll
            for (int r = 0; r < 4; ++r) {
                const int gm = tm0 + wm + i*16 + quad*4 + r;
                const int gn = tn0 + wn + j*16 + row16;
                float v = acc[i][j][r];
                if (MODE == 0) {
                    ((bf16*)C)[(size_t)gm*ldc + gn] = f2b(v);
                } else if (MODE == 1) {
                    size_t gi = (row_off + gm)*(size_t)ldc + gn;
                    v += ldin(resid, gi, f32);
                    stout(C, gi, f32, v);
                } else if (MODE == 2) {
                    v += ldin(bias, gn, f32);
                    v = 0.5f*v*(1.f + erff(v*0.70710678118f));
                    ((bf16*)C)[(size_t)gm*ldc + gn] = f2b(v);
                } else {
                    size_t gi = (row_off + gm)*(size_t)ldc + gn;
                    v += ldin(bias, gn, f32) + ldin(resid, gi, f32);
                    stout(C, gi, f32, v);
                }
            }
        }
    }
}

extern "C" void kernel_launch(void* const* d_in, const int* in_sizes, int n_in,
                              void* d_out, int out_size, void* d_ws, size_t ws_size,
                              hipStream_t stream) {
    const void* x       = d_in[0];
    const void* norm_w  = d_in[1];
    const void* norm_b  = d_in[2];
    const void* dw_w    = d_in[3];
    const void* dw_b    = d_in[4];
    const void* whg1    = d_in[5];
    const void* wout1   = d_in[6];
    const void* whg2    = d_in[7];
    const void* wout2   = d_in[8];
    const void* norm2_w = d_in[9];
    const void* norm2_b = d_in[10];
    const void* p1_w    = d_in[11];
    const void* p1_b    = d_in[12];
    const void* p2_w    = d_in[13];
    const void* p2_b    = d_in[14];
    void* out = d_out;
    char* ws = (char*)d_ws;

    const size_t WSZ = 5898240;   // transposed weights (bf16)

    int CH = 16;
    for (;;) {
        size_t need = 256 + WSZ + (size_t)CH * SEQ * 4608;
        if (need <= ws_size || CH == 2) break;
        CH >>= 1;
    }
    const int NC = N_BATCH / CH;
    const int CHROWS = CH * SEQ;

    int* flag = (int*)ws;
    char* wb = ws + 256;
    bf16* WhgT1  = (bf16*)(wb);                  // 1536 x 384
    bf16* WhgT2  = (bf16*)(wb + 1179648);        // 1536 x 384
    bf16* WoutT1 = (bf16*)(wb + 2359296);        // 384 x 768
    bf16* WoutT2 = (bf16*)(wb + 2949120);        // 384 x 768
    bf16* P1T    = (bf16*)(wb + 3538944);        // 1536 x 384
    bf16* P2T    = (bf16*)(wb + 4718592);        // 384 x 1536
    char* dyn = ws + 256 + WSZ;
    bf16* h_ln_c   = (bf16*)(dyn);
    bf16* h_conv_c = (bf16*)(dyn + (size_t)CHROWS*DIM*2);
    bf16* Gbuf     = (bf16*)(dyn + 2*(size_t)CHROWS*DIM*2);
    bf16* mid_ln_c = h_ln_c;
    float* Aseg = (float*)h_ln_c;
    float* Bseg = Aseg + (size_t)CH*NSEG*DI;
    float* Pseg = Bseg + (size_t)CH*NSEG*DI;

    detect_kernel<<<1, 256, 0, stream>>>((const unsigned short*)x, flag);

    transpose_kernel<<<(384*1536+255)/256, 256, 0, stream>>>(whg1, WhgT1, 384, 1536, flag);
    transpose_kernel<<<(384*1536+255)/256, 256, 0, stream>>>(whg2, WhgT2, 384, 1536, flag);
    transpose_kernel<<<(768*384+255)/256, 256, 0, stream>>>(wout1, WoutT1, 768, 384, flag);
    transpose_kernel<<<(768*384+255)/256, 256, 0, stream>>>(wout2, WoutT2, 768, 384, flag);
    transpose_kernel<<<(384*1536+255)/256, 256, 0, stream>>>(p1_w, P1T, 384, 1536, flag);
    transpose_kernel<<<(1536*384+255)/256, 256, 0, stream>>>(p2_w, P2T, 1536, 384, flag);

    for (int pass = 0; pass < 2; ++pass) {
        const bf16* WhgT  = pass ? WhgT2  : WhgT1;
        const bf16* WoutT = pass ? WoutT2 : WoutT1;
        for (int ck = 0; ck < NC; ++ck) {
            const size_t roff = (size_t)ck * CHROWS;
            if (pass == 0 || NC > 1) {
                ln_kernel<<<CHROWS, 64, 0, stream>>>(x, norm_w, norm_b, h_ln_c, roff, flag);
                dwconv_kernel<<<dim3(28, 7, CH), 192, 0, stream>>>(h_ln_c, dw_w, dw_b, h_conv_c, flag);
            }
            gemm_kernel<0><<<dim3(1536/128, CHROWS/128), 256, 0, stream>>>(
                h_conv_c, DIM, WhgT, Gbuf, 2*DI, DIM, 0, nullptr, nullptr, flag);
            scan_p1<<<dim3(12, NSEG, CH), 64, 0, stream>>>(Gbuf, Aseg, Bseg, pass);
            scan_p2<<<dim3(12, CH), 64, 0, stream>>>(Aseg, Bseg, Pseg);
            scan_p3<<<dim3(12, NSEG, CH), 64, 0, stream>>>(Gbuf, Pseg, pass);
            const void* resid = pass ? (const void*)out : x;
            gemm_kernel<1><<<dim3(DIM/128, CHROWS/128), 256, 0, stream>>>(
                Gbuf, 2*DI, WoutT, out, DIM, DI, roff, nullptr, resid, flag);
        }
    }

    for (int ck = 0; ck < NC; ++ck) {
        const size_t roff = (size_t)ck * CHROWS;
        ln_kernel<<<CHROWS, 64, 0, stream>>>(out, norm2_w, norm2_b, mid_ln_c, roff, flag);
        gemm_kernel<2><<<dim3(1536/128, CHROWS/128), 256, 0, stream>>>(
            mid_ln_c, DIM, P1T, Gbuf, 1536, DIM, 0, p1_b, nullptr, flag);
        gemm_kernel<3><<<dim3(DIM/128, CHROWS/128), 256, 0, stream>>>(
            Gbuf, 1536, P2T, out, DIM, 1536, roff, p2_b, out, flag);
    }
}